// Round 1
// baseline (2827.556 us; speedup 1.0000x reference)
//
#include <hip/hip_runtime.h>
#include <hip/hip_bf16.h>

// Problem constants
#define NROWS 32768
#define DDIM  512
#define KSZ_  4096
#define EMA_DECAY_ 0.99f
#define EPS_ 1e-5f

// GEMM-argmin tiling
#define BM 128
#define BN 64
#define BK 16
#define LSTR 20          // BK + 4 pad (80B rows: 16B-aligned, conflict-free/2-way patterns)
#define CSPLIT 4         // K-dim split across blocks

// ---------------------------------------------------------------------------
// Kernel 1: Kt2[j] = sum_d K[j][d]^2   (one wave per row)
// ---------------------------------------------------------------------------
__global__ __launch_bounds__(256) void kt2_kernel(const float* __restrict__ K,
                                                  float* __restrict__ Kt2) {
    int gid  = blockIdx.x * 256 + threadIdx.x;
    int row  = gid >> 6;
    int lane = threadIdx.x & 63;
    const float* kr = K + (size_t)row * DDIM;
    float s = 0.f;
#pragma unroll
    for (int u = 0; u < 2; u++) {
        float4 v = *(const float4*)&kr[u * 256 + lane * 4];
        s += v.x * v.x + v.y * v.y + v.z * v.z + v.w * v.w;
    }
#pragma unroll
    for (int off = 1; off < 64; off <<= 1) s += __shfl_xor(s, off, 64);
    if (lane == 0) Kt2[row] = s;
}

// ---------------------------------------------------------------------------
// Kernel 2: fused fp32 GEMM + argmin. Each block: BM rows x (KSZ/CSPLIT) cols.
// score = 0.5*|K[j]|^2 - f.K[j]  (same argmin as squared distance)
// ---------------------------------------------------------------------------
__global__ __launch_bounds__(256, 2) void argmin_kernel(
    const float* __restrict__ f, const float* __restrict__ K,
    const float* __restrict__ Kt2,
    float* __restrict__ bestd, int* __restrict__ bestidx) {
    __shared__ float As[BM * LSTR];
    __shared__ float Bs[BN * LSTR];

    const int tid   = threadIdx.x;
    const int row0  = blockIdx.x * BM;
    const int split = blockIdx.y;
    const int col0  = split * (KSZ_ / CSPLIT);

    const int tx = tid & 15;   // col group
    const int ty = tid >> 4;   // row group (0..15)

    float best[8];
    int   bidx[8];
#pragma unroll
    for (int r = 0; r < 8; r++) { best[r] = 3.4e38f; bidx[r] = -1; }

    for (int chunk = 0; chunk < (KSZ_ / CSPLIT) / BN; ++chunk) {
        const int c0 = col0 + chunk * BN;
        float acc[8][4];
#pragma unroll
        for (int r = 0; r < 8; r++)
#pragma unroll
            for (int c = 0; c < 4; c++) acc[r][c] = 0.f;

        for (int kk0 = 0; kk0 < DDIM; kk0 += BK) {
            __syncthreads();
            // stage A tile: 128x16 floats = 512 float4, 2 per thread
#pragma unroll
            for (int v = 0; v < 2; v++) {
                int idx = tid + v * 256;
                int r = idx >> 2, kp = idx & 3;
                float4 t = *(const float4*)&f[(size_t)(row0 + r) * DDIM + kk0 + kp * 4];
                *(float4*)&As[r * LSTR + kp * 4] = t;
            }
            // stage B tile: 64x16 floats = 256 float4, 1 per thread
            {
                int r = tid >> 2, kp = tid & 3;
                float4 t = *(const float4*)&K[(size_t)(c0 + r) * DDIM + kk0 + kp * 4];
                *(float4*)&Bs[r * LSTR + kp * 4] = t;
            }
            __syncthreads();
#pragma unroll
            for (int kk = 0; kk < BK; kk += 4) {
                float4 a4[8], b4[4];
#pragma unroll
                for (int r = 0; r < 8; r++)
                    a4[r] = *(const float4*)&As[(ty + 16 * r) * LSTR + kk];
#pragma unroll
                for (int c = 0; c < 4; c++)
                    b4[c] = *(const float4*)&Bs[(tx + 16 * c) * LSTR + kk];
#pragma unroll
                for (int r = 0; r < 8; r++)
#pragma unroll
                    for (int c = 0; c < 4; c++) {
                        acc[r][c] = __builtin_fmaf(a4[r].x, b4[c].x, acc[r][c]);
                        acc[r][c] = __builtin_fmaf(a4[r].y, b4[c].y, acc[r][c]);
                        acc[r][c] = __builtin_fmaf(a4[r].z, b4[c].z, acc[r][c]);
                        acc[r][c] = __builtin_fmaf(a4[r].w, b4[c].w, acc[r][c]);
                    }
            }
        }
        // epilogue: argmin update
        float kt2c[4];
#pragma unroll
        for (int c = 0; c < 4; c++) kt2c[c] = Kt2[c0 + tx + 16 * c];
#pragma unroll
        for (int r = 0; r < 8; r++) {
            float d = 3.4e38f; int bi = 0x7fffffff;
#pragma unroll
            for (int c = 0; c < 4; c++) {
                int col = c0 + tx + 16 * c;
                float s = 0.5f * kt2c[c] - acc[r][c];
                if (s < d || (s == d && col < bi)) { d = s; bi = col; }
            }
            // min across the 16-lane tx group (lanes differ in bits 0..3)
#pragma unroll
            for (int off = 1; off < 16; off <<= 1) {
                float od = __shfl_xor(d, off, 64);
                int   oi = __shfl_xor(bi, off, 64);
                if (od < d || (od == d && oi < bi)) { d = od; bi = oi; }
            }
            if (d < best[r] || (d == best[r] && bi < bidx[r])) { best[r] = d; bidx[r] = bi; }
        }
    }
    if (tx == 0) {
#pragma unroll
        for (int r = 0; r < 8; r++) {
            int row = row0 + ty + 16 * r;
            bestd[(size_t)row * CSPLIT + split]   = best[r];
            bestidx[(size_t)row * CSPLIT + split] = bidx[r];
        }
    }
}

// ---------------------------------------------------------------------------
// Kernel 3: per-row split-reduce, gather K[k1] -> f_ipmlm, loss partial,
// scatter counts/dw via atomics. One wave per row.
// ---------------------------------------------------------------------------
__global__ __launch_bounds__(256) void gather_kernel(
    const float* __restrict__ f, const float* __restrict__ K,
    const float* __restrict__ bestd, const int* __restrict__ bestidx,
    float* __restrict__ out_fipm, float* __restrict__ loss_sum,
    float* __restrict__ counts, float* __restrict__ dw) {
    int gid  = blockIdx.x * 256 + threadIdx.x;
    int row  = gid >> 6;
    int lane = threadIdx.x & 63;

    float d = bestd[(size_t)row * CSPLIT];
    int  bi = bestidx[(size_t)row * CSPLIT];
#pragma unroll
    for (int s = 1; s < CSPLIT; s++) {
        float od = bestd[(size_t)row * CSPLIT + s];
        int   oi = bestidx[(size_t)row * CSPLIT + s];
        if (od < d || (od == d && oi < bi)) { d = od; bi = oi; }
    }

    const float* frow = f + (size_t)row * DDIM;
    const float* krow = K + (size_t)bi * DDIM;
    float lsum = 0.f;
#pragma unroll
    for (int u = 0; u < 2; u++) {
        int off = u * 256 + lane * 4;
        float4 fv = *(const float4*)&frow[off];
        float4 kv = *(const float4*)&krow[off];
        *(float4*)&out_fipm[(size_t)row * DDIM + off] = kv;
        float dx = kv.x - fv.x, dy = kv.y - fv.y, dz = kv.z - fv.z, dwv = kv.w - fv.w;
        lsum += dx * dx + dy * dy + dz * dz + dwv * dwv;
        float* dst = &dw[(size_t)bi * DDIM + off];
        atomicAdd(dst + 0, fv.x);
        atomicAdd(dst + 1, fv.y);
        atomicAdd(dst + 2, fv.z);
        atomicAdd(dst + 3, fv.w);
    }
#pragma unroll
    for (int off = 1; off < 64; off <<= 1) lsum += __shfl_xor(lsum, off, 64);
    if (lane == 0) {
        atomicAdd(loss_sum, lsum);
        atomicAdd(&counts[bi], 1.0f);
    }
}

// ---------------------------------------------------------------------------
// Kernel 4: new_ecs = 0.99*ecs + 0.01*counts; n = sum(new_ecs)
// ---------------------------------------------------------------------------
__global__ __launch_bounds__(256) void ecs_kernel(
    const float* __restrict__ ecs_in, const float* __restrict__ counts,
    float* __restrict__ out_ecs, float* __restrict__ n_sum) {
    int i = blockIdx.x * 256 + threadIdx.x;
    float v = ecs_in[i] * EMA_DECAY_ + (1.0f - EMA_DECAY_) * counts[i];
    out_ecs[i] = v;
    float s = v;
#pragma unroll
    for (int off = 1; off < 64; off <<= 1) s += __shfl_xor(s, off, 64);
    if ((threadIdx.x & 63) == 0) atomicAdd(n_sum, s);
}

// ---------------------------------------------------------------------------
// Kernel 5: new_ema_w = 0.99*ema_w + 0.01*dw; new_K = new_ema_w / smoothed
// out_K / out_emaw are at odd float offsets -> scalar stores only.
// ---------------------------------------------------------------------------
__global__ __launch_bounds__(256) void final_kernel(
    const float* __restrict__ ema_w, const float* __restrict__ dw,
    const float* __restrict__ out_ecs, const float* __restrict__ n_sum,
    const float* __restrict__ loss_sum,
    float* __restrict__ out_K, float* __restrict__ out_emaw,
    float* __restrict__ out_loss) {
    int idx4 = blockIdx.x * 256 + threadIdx.x;   // 0..524287 (float4 granules)
    int row  = idx4 >> 7;                        // 128 float4 per row
    float n  = *n_sum;
    float smoothed = (out_ecs[row] + EPS_) / (n + KSZ_ * EPS_) * n;
    float inv = 1.0f / smoothed;
    size_t e = (size_t)idx4 * 4;
    float4 wv = *(const float4*)&ema_w[e];
    float4 dv = *(const float4*)&dw[e];
    float w0 = EMA_DECAY_ * wv.x + (1.0f - EMA_DECAY_) * dv.x;
    float w1 = EMA_DECAY_ * wv.y + (1.0f - EMA_DECAY_) * dv.y;
    float w2 = EMA_DECAY_ * wv.z + (1.0f - EMA_DECAY_) * dv.z;
    float w3 = EMA_DECAY_ * wv.w + (1.0f - EMA_DECAY_) * dv.w;
    out_emaw[e + 0] = w0; out_emaw[e + 1] = w1;
    out_emaw[e + 2] = w2; out_emaw[e + 3] = w3;
    out_K[e + 0] = w0 * inv; out_K[e + 1] = w1 * inv;
    out_K[e + 2] = w2 * inv; out_K[e + 3] = w3 * inv;
    if (idx4 == 0) *out_loss = *loss_sum * (1.0f / 16777216.0f);
}

// ---------------------------------------------------------------------------
// Workspace layout (float offsets):
//   0        Kt2        [4096]
//   4096     bestd      [32768*4]
//   135168   bestidx    [32768*4] (int)
//   266240   counts     [4096]      <- zeroed each launch
//   270336   dw         [4096*512]  <- zeroed
//   2367488  loss_sum   [1]         <- zeroed
//   2367489  n_sum      [1]         <- zeroed
// total 2367490 floats (~9.5 MB)
// ---------------------------------------------------------------------------
extern "C" void kernel_launch(void* const* d_in, const int* in_sizes, int n_in,
                              void* d_out, int out_size, void* d_ws, size_t ws_size,
                              hipStream_t stream) {
    const float* f     = (const float*)d_in[0];
    const float* K     = (const float*)d_in[1];
    const float* ecs   = (const float*)d_in[2];
    const float* ema_w = (const float*)d_in[3];

    float* ws       = (float*)d_ws;
    float* Kt2      = ws;
    float* bestd    = ws + 4096;
    int*   bestidx  = (int*)(ws + 135168);
    float* counts   = ws + 266240;
    float* dw       = ws + 270336;
    float* loss_sum = ws + 2367488;
    float* n_sum    = ws + 2367489;

    float* out      = (float*)d_out;
    float* out_fipm = out;                    // 16777216
    float* out_loss = out + 16777216;         // 1
    float* out_K    = out + 16777217;         // 2097152
    float* out_ecs  = out + 18874369;         // 4096
    float* out_emaw = out + 18878465;         // 2097152

    // zero accumulators: counts + dw + loss + n (contiguous)
    hipMemsetAsync(counts, 0, (size_t)(4096 + 2097152 + 2) * sizeof(float), stream);

    kt2_kernel<<<KSZ_ * 64 / 256, 256, 0, stream>>>(K, Kt2);

    dim3 grid(NROWS / BM, CSPLIT);
    argmin_kernel<<<grid, 256, 0, stream>>>(f, K, Kt2, bestd, bestidx);

    gather_kernel<<<NROWS * 64 / 256, 256, 0, stream>>>(
        f, K, bestd, bestidx, out_fipm, loss_sum, counts, dw);

    ecs_kernel<<<KSZ_ / 256, 256, 0, stream>>>(ecs, counts, out_ecs, n_sum);

    final_kernel<<<(KSZ_ * DDIM / 4) / 256, 256, 0, stream>>>(
        ema_w, dw, out_ecs, n_sum, loss_sum, out_K, out_emaw, out_loss);
}